// Round 5
// baseline (922.515 us; speedup 1.0000x reference)
//
#include <hip/hip_runtime.h>
#include <hip/hip_bf16.h>
#include <stdint.h>

#define N_NODES 100000
#define N_EDGES 1600000
#define FEAT 128
#define EMB 128
#define N_ROOTS 4096

#define BUCKET_BITS 9
#define BUCKET_NODES 512
#define NBUCK ((N_NODES + BUCKET_NODES - 1) / BUCKET_NODES)  // 196
#define BUCK_CAP 12288
#define BIN_CHUNK 4096
#define NB_BIN ((N_EDGES + BIN_CHUNK - 1) / BIN_CHUNK)       // 391

#define SLAB16 ((size_t)N_NODES * 16)   // ushorts per 16-col slab
#define SLAB8  ((size_t)N_NODES * 8)    // dwords per slab

typedef __attribute__((ext_vector_type(4))) float f32x4;
typedef __attribute__((ext_vector_type(8))) short bf16x8;

__device__ __forceinline__ ushort f2b(float f) {
  uint32_t u = __float_as_uint(f);
  uint32_t r = (u + 0x7FFFu + ((u >> 16) & 1u)) >> 16;  // RNE
  return (ushort)r;
}

// f32 row-major [n][128] -> bf16 sliced [8 slabs][n][16]
__global__ void k_cvt_sliced(const float* __restrict__ in, ushort* __restrict__ out, int n) {
  int g = blockIdx.x * blockDim.x + threadIdx.x;  // one 8-col group
  int stride = gridDim.x * blockDim.x;
  int total = n * 16;
  for (; g < total; g += stride) {
    int node = g >> 4, cg = g & 15;
    const float4* p = (const float4*)(in + (size_t)node * 128 + cg * 8);
    float4 v0 = p[0], v1 = p[1];
    uint32_t w0 = (uint32_t)f2b(v0.x) | ((uint32_t)f2b(v0.y) << 16);
    uint32_t w1 = (uint32_t)f2b(v0.z) | ((uint32_t)f2b(v0.w) << 16);
    uint32_t w2 = (uint32_t)f2b(v1.x) | ((uint32_t)f2b(v1.y) << 16);
    uint32_t w3 = (uint32_t)f2b(v1.z) | ((uint32_t)f2b(v1.w) << 16);
    uint4 pk = make_uint4(w0, w1, w2, w3);
    int slab = cg >> 1, off8 = (cg & 1) * 8;
    *(uint4*)(out + (size_t)slab * SLAB16 + (size_t)node * 16 + off8) = pk;
  }
}

// ---- bucketed CSR build (unchanged from R3) ----
__global__ __launch_bounds__(256) void k_bin(const int* __restrict__ srcA, const int* __restrict__ dstA,
                                             int* __restrict__ bucket_cnt, int* __restrict__ binned) {
  __shared__ int hist[NBUCK];
  __shared__ int lscan[NBUCK];
  __shared__ int rsv[NBUCK];
  __shared__ int lpos[NBUCK];
  __shared__ int ws[4];
  __shared__ int2 ent[BIN_CHUNK];
  int t = threadIdx.x;
  int e0 = blockIdx.x * BIN_CHUNK;
  int cnt = min(BIN_CHUNK, N_EDGES - e0);
  for (int i = t; i < NBUCK; i += 256) hist[i] = 0;
  __syncthreads();
  for (int j = t; j < cnt; j += 256) atomicAdd(&hist[dstA[e0 + j] >> BUCKET_BITS], 1);
  __syncthreads();
  {
    int lane = t & 63, wv = t >> 6;
    int v = (t < NBUCK) ? hist[t] : 0;
    int inc = v;
    for (int d = 1; d < 64; d <<= 1) { int x = __shfl_up(inc, d); if (lane >= d) inc += x; }
    if (lane == 63) ws[wv] = inc;
    __syncthreads();
    int wbase = 0;
    for (int k = 0; k < wv; ++k) wbase += ws[k];
    if (t < NBUCK) {
      int excl = wbase + inc - v;
      lscan[t] = excl;
      lpos[t] = excl;
      rsv[t] = (v > 0) ? atomicAdd(&bucket_cnt[t], v) : 0;
    }
  }
  __syncthreads();
  for (int j = t; j < cnt; j += 256) {
    int s = srcA[e0 + j], d = dstA[e0 + j];
    int p = atomicAdd(&lpos[d >> BUCKET_BITS], 1);
    ent[p] = make_int2(s, d);
  }
  __syncthreads();
  for (int j = t; j < cnt; j += 256) {
    int2 E = ent[j];
    int b = E.y >> BUCKET_BITS;
    int pos = rsv[b] + (j - lscan[b]);
    if (pos < BUCK_CAP)
      binned[b * BUCK_CAP + pos] = (E.x << BUCKET_BITS) | (E.y & (BUCKET_NODES - 1));
  }
}

__global__ __launch_bounds__(256) void k_bucket_scan(const int* __restrict__ bucket_cnt,
                                                     int* __restrict__ bucket_base,
                                                     int* __restrict__ off_last) {
  __shared__ int ws[4];
  int t = threadIdx.x;
  int lane = t & 63, wv = t >> 6;
  int v = (t < NBUCK) ? bucket_cnt[t] : 0;
  int inc = v;
  for (int d = 1; d < 64; d <<= 1) { int x = __shfl_up(inc, d); if (lane >= d) inc += x; }
  if (lane == 63) ws[wv] = inc;
  __syncthreads();
  int wbase = 0;
  for (int k = 0; k < wv; ++k) wbase += ws[k];
  if (t < NBUCK) bucket_base[t] = wbase + inc - v;
  if (t == NBUCK - 1) *off_last = wbase + inc;
}

__global__ __launch_bounds__(512) void k_csr(const int* __restrict__ binned,
                                             const int* __restrict__ bucket_cnt,
                                             const int* __restrict__ bucket_base,
                                             int* __restrict__ off, int* __restrict__ srcs) {
  __shared__ int deg[BUCKET_NODES];
  __shared__ int sAb[BUCKET_NODES];
  __shared__ int sBb[BUCKET_NODES];
  __shared__ int pos[BUCKET_NODES];
  __shared__ int epk[BUCK_CAP];
  int b = blockIdx.x;
  int t = threadIdx.x;
  int cnt = min(bucket_cnt[b], BUCK_CAP);
  int gbase = bucket_base[b];
  int n0 = b * BUCKET_NODES;
  int nn = min(BUCKET_NODES, N_NODES - n0);
  deg[t] = 0;
  __syncthreads();
  for (int j = t; j < cnt; j += 512) {
    int p = binned[b * BUCK_CAP + j];
    epk[j] = p;
    atomicAdd(&deg[p & (BUCKET_NODES - 1)], 1);
  }
  __syncthreads();
  int* sA = sAb; int* sB = sBb;
  sA[t] = deg[t];
  __syncthreads();
  for (int d = 1; d < 512; d <<= 1) {
    int x = sA[t];
    if (t >= d) x += sA[t - d];
    sB[t] = x;
    __syncthreads();
    int* tp = sA; sA = sB; sB = tp;
  }
  int ex = sA[t] - deg[t];
  pos[t] = ex;
  if (t < nn) off[n0 + t] = gbase + ex;
  __syncthreads();
  for (int j = t; j < cnt; j += 512) {
    int p = epk[j];
    int q = atomicAdd(&pos[p & (BUCKET_NODES - 1)], 1);
    srcs[gbase + q] = p >> BUCKET_BITS;
  }
}

// sliced-layout GEMM: A (bf16 slabs, A0|A1 split at k=128, optional relu on A0) @ W[K][128]
// output written sliced.
__global__ __launch_bounds__(256) void k_gemm(
    const ushort* __restrict__ A0, const ushort* __restrict__ A1,
    const float* __restrict__ W, ushort* __restrict__ out, int n, int K, int relu0)
{
  extern __shared__ char smem[];  // W^T swizzled: (k,c) -> byte c*2K + ((2k)^((c&7)<<4))
  const int KC = K * 128;
  for (int idx = threadIdx.x; idx < KC; idx += 256) {
    int k = idx >> 7, c = idx & 127;
    ushort b = f2b(W[idx]);
    *(ushort*)(smem + c * (K * 2) + ((k * 2) ^ ((c & 7) << 4))) = b;
  }
  __syncthreads();

  int lane = threadIdx.x & 63;
  int wv = threadIdx.x >> 6;
  int rowBase = blockIdx.x * 128 + wv * 32;
  int rl = lane & 15;
  int kh = lane >> 4;
  int r0 = rowBase + rl, r1 = r0 + 16;
  int r0c = min(r0, n - 1), r1c = min(r1, n - 1);

  f32x4 acc[2][8];
#pragma unroll
  for (int i = 0; i < 2; ++i)
#pragma unroll
    for (int j = 0; j < 8; ++j)
      acc[i][j] = (f32x4){0.f, 0.f, 0.f, 0.f};

  int nks = K >> 5;
  for (int ks = 0; ks < nks; ++ks) {
    const ushort* Asrc = (ks < 4) ? A0 : A1;
    int kof = ((ks & 3) << 5) + (kh << 3);
    const ushort* ap = Asrc + (size_t)(kof >> 4) * SLAB16 + (kof & 15);
    bf16x8 a0 = *(const bf16x8*)(ap + (size_t)r0c * 16);
    bf16x8 a1 = *(const bf16x8*)(ap + (size_t)r1c * 16);
    if (relu0 && ks < 4) {   // relu on bf16: negative -> 0
#pragma unroll
      for (int q = 0; q < 8; ++q) {
        short v0 = a0[q]; a0[q] = (short)(v0 & ~(v0 >> 15));
        short v1 = a1[q]; a1[q] = (short)(v1 & ~(v1 >> 15));
      }
    }
    int kk = (ks << 5) + (kh << 3);
#pragma unroll
    for (int ct = 0; ct < 8; ++ct) {
      int col = (ct << 4) + rl;
      bf16x8 b = *(const bf16x8*)(smem + col * (K * 2) + ((kk * 2) ^ ((col & 7) << 4)));
      acc[0][ct] = __builtin_amdgcn_mfma_f32_16x16x32_bf16(a0, b, acc[0][ct], 0, 0, 0);
      acc[1][ct] = __builtin_amdgcn_mfma_f32_16x16x32_bf16(a1, b, acc[1][ct], 0, 0, 0);
    }
  }
  // C layout: col = lane&15 (=rl), row = kh*4 + reg; slab = ct, in-slab col = rl
#pragma unroll
  for (int ri = 0; ri < 2; ++ri)
#pragma unroll
    for (int ct = 0; ct < 8; ++ct) {
#pragma unroll
      for (int j = 0; j < 4; ++j) {
        int row = rowBase + ri * 16 + kh * 4 + j;
        if (row < n) out[(size_t)ct * SLAB16 + (size_t)row * 16 + rl] = f2b(acc[ri][ct][j]);
      }
    }
}

// column-sliced segment sum: block -> slice = blockIdx%8 (XCD-pinned), 32 nodes/block.
// wave lanes = (slot 0..7) x (col-dword 0..7); 8 edges gathered per instruction.
__global__ __launch_bounds__(256) void k_aggr(
    const ushort* __restrict__ hlin_s, const int* __restrict__ off, const int* __restrict__ srcs,
    const float* __restrict__ bias, ushort* __restrict__ hbf_s, float* __restrict__ outf,
    int n, int first, int last)
{
  int slice = blockIdx.x & 7;
  int chunk = blockIdx.x >> 3;
  int wv = threadIdx.x >> 6, lane = threadIdx.x & 63;
  int slot = lane >> 3, cd = lane & 7;
  const uint32_t* slab  = (const uint32_t*)hlin_s + (size_t)slice * SLAB8;
  const uint32_t* hslab = (const uint32_t*)hbf_s + (size_t)slice * SLAB8;
  float2 bv = ((const float2*)bias)[slice * 8 + cd];
  for (int ni = 0; ni < 8; ++ni) {
    int node = chunk * 32 + wv * 8 + ni;
    if (node >= n) return;
    int s = off[node], e = off[node + 1];
    float a0 = 0.f, a1 = 0.f;
    for (int j = s; j < e; j += 16) {
      int j1 = j + slot, j2 = j + 8 + slot;
      uint32_t u1 = 0, u2 = 0;
      if (j1 < e) { int s1 = srcs[j1]; u1 = slab[(size_t)s1 * 8 + cd]; }
      if (j2 < e) { int s2 = srcs[j2]; u2 = slab[(size_t)s2 * 8 + cd]; }
      a0 += __uint_as_float(u1 << 16) + __uint_as_float(u2 << 16);
      a1 += __uint_as_float(u1 & 0xFFFF0000u) + __uint_as_float(u2 & 0xFFFF0000u);
    }
    a0 += __shfl_xor(a0, 8); a0 += __shfl_xor(a0, 16); a0 += __shfl_xor(a0, 32);
    a1 += __shfl_xor(a1, 8); a1 += __shfl_xor(a1, 16); a1 += __shfl_xor(a1, 32);
    if (slot == 0) {
      float h0, h1;
      if (first) {
        h0 = a0 + bv.x; h1 = a1 + bv.y;
      } else {
        uint32_t up = hslab[(size_t)node * 8 + cd];
        h0 = __uint_as_float(up << 16) + a0 + bv.x;
        h1 = __uint_as_float(up & 0xFFFF0000u) + a1 + bv.y;
      }
      if (last) {
        if (node < N_ROOTS)
          *(float2*)(outf + (size_t)node * 128 + slice * 16 + cd * 2) = make_float2(h0, h1);
      } else {
        uint32_t pk = (uint32_t)f2b(h0) | ((uint32_t)f2b(h1) << 16);
        ((uint32_t*)hbf_s)[(size_t)slice * SLAB8 + (size_t)node * 8 + cd] = pk;
      }
    }
  }
}

extern "C" void kernel_launch(void* const* d_in, const int* in_sizes, int n_in,
                              void* d_out, int out_size, void* d_ws, size_t ws_size,
                              hipStream_t stream) {
  const float* x = (const float*)d_in[0];
  const int* ei  = (const int*)d_in[1];
  const int* src = ei;
  const int* dst = ei + N_EDGES;
  const float* Wp[4] = {(const float*)d_in[4], (const float*)d_in[6],
                        (const float*)d_in[8], (const float*)d_in[10]};
  const float* bp[4] = {(const float*)d_in[5], (const float*)d_in[7],
                        (const float*)d_in[9], (const float*)d_in[11]};

  char* w = (char*)d_ws;
  auto alloc = [&](size_t bytes) {
    char* p = w;
    w += (bytes + 255) & ~(size_t)255;
    return p;
  };
  ushort* xs       = (ushort*)alloc((size_t)N_NODES * 128 * 2);  // x, sliced
  ushort* hbf_s    = (ushort*)alloc((size_t)N_NODES * 128 * 2);  // running h, sliced
  ushort* hlin_s   = (ushort*)alloc((size_t)N_NODES * 128 * 2);  // per-layer messages, sliced
  int*    off      = (int*)   alloc((size_t)(N_NODES + 1) * 4);
  int*    srcs     = (int*)   alloc((size_t)N_EDGES * 4);
  int*    binned   = (int*)   alloc((size_t)NBUCK * BUCK_CAP * 4);
  int*    bucket_cnt  = (int*)alloc((size_t)NBUCK * 4);
  int*    bucket_base = (int*)alloc((size_t)(NBUCK + 1) * 4);
  if ((size_t)(w - (char*)d_ws) > ws_size) return;

  hipMemsetAsync(bucket_cnt, 0, (size_t)NBUCK * 4, stream);
  k_cvt_sliced<<<2048, 256, 0, stream>>>(x, xs, N_NODES);
  k_bin<<<NB_BIN, 256, 0, stream>>>(src, dst, bucket_cnt, binned);
  k_bucket_scan<<<1, 256, 0, stream>>>(bucket_cnt, bucket_base, off + N_NODES);
  k_csr<<<NBUCK, 512, 0, stream>>>(binned, bucket_cnt, bucket_base, off, srcs);

  int gblocks = (N_NODES + 127) / 128;
  int ablocks = ((N_NODES + 31) / 32) * 8;   // x8 slices, slice = blockIdx % 8 (XCD-pinned)
  // layer 0
  k_gemm<<<gblocks, 256, 128 * 128 * 2, stream>>>(xs, xs, Wp[0], hlin_s, N_NODES, 128, 0);
  k_aggr<<<ablocks, 256, 0, stream>>>(hlin_s, off, srcs, bp[0], hbf_s, (float*)d_out, N_NODES, 1, 0);
  // layers 1..3
  for (int l = 1; l < 4; ++l) {
    k_gemm<<<gblocks, 256, 256 * 128 * 2, stream>>>(hbf_s, xs, Wp[l], hlin_s, N_NODES, 256, 1);
    k_aggr<<<ablocks, 256, 0, stream>>>(hlin_s, off, srcs, bp[l], hbf_s, (float*)d_out,
                                        N_NODES, 0, (l == 3) ? 1 : 0);
  }
}

// Round 6
// 403.386 us; speedup vs baseline: 2.2869x; 2.2869x over previous
//
#include <hip/hip_runtime.h>
#include <hip/hip_bf16.h>
#include <stdint.h>

#define N_NODES 100000
#define N_EDGES 1600000
#define FEAT 128
#define EMB 128
#define N_ROOTS 4096

#define BUCKET_BITS 9
#define BUCKET_NODES 512
#define NBUCK ((N_NODES + BUCKET_NODES - 1) / BUCKET_NODES)  // 196
#define BUCK_CAP 12288
#define BIN_CHUNK 4096
#define NB_BIN ((N_EDGES + BIN_CHUNK - 1) / BIN_CHUNK)       // 391
#define SRCS_CAP (N_EDGES + N_NODES * 8)                     // padded CSR capacity

typedef __attribute__((ext_vector_type(4))) float f32x4;
typedef __attribute__((ext_vector_type(8))) short bf16x8;

__device__ __forceinline__ ushort f2b(float f) {
  uint32_t u = __float_as_uint(f);
  uint32_t r = (u + 0x7FFFu + ((u >> 16) & 1u)) >> 16;  // RNE
  return (ushort)r;
}

__global__ void k_cvt_bf16(const float* __restrict__ in, ushort* __restrict__ out, int n4) {
  int i = blockIdx.x * blockDim.x + threadIdx.x;
  int stride = gridDim.x * blockDim.x;
  for (; i < n4; i += stride) {
    float4 v = ((const float4*)in)[i];
    ushort4 o;
    o.x = f2b(v.x); o.y = f2b(v.y); o.z = f2b(v.z); o.w = f2b(v.w);
    ((ushort4*)out)[i] = o;
  }
}

// ---- bucketed CSR build, padded to 8-edge multiples per node ----
__global__ __launch_bounds__(256) void k_bin(const int* __restrict__ srcA, const int* __restrict__ dstA,
                                             int* __restrict__ bucket_cnt, int* __restrict__ binned) {
  __shared__ int hist[NBUCK];
  __shared__ int lscan[NBUCK];
  __shared__ int rsv[NBUCK];
  __shared__ int lpos[NBUCK];
  __shared__ int ws[4];
  __shared__ int2 ent[BIN_CHUNK];
  int t = threadIdx.x;
  int e0 = blockIdx.x * BIN_CHUNK;
  int cnt = min(BIN_CHUNK, N_EDGES - e0);
  for (int i = t; i < NBUCK; i += 256) hist[i] = 0;
  __syncthreads();
  for (int j = t; j < cnt; j += 256) atomicAdd(&hist[dstA[e0 + j] >> BUCKET_BITS], 1);
  __syncthreads();
  {
    int lane = t & 63, wv = t >> 6;
    int v = (t < NBUCK) ? hist[t] : 0;
    int inc = v;
    for (int d = 1; d < 64; d <<= 1) { int x = __shfl_up(inc, d); if (lane >= d) inc += x; }
    if (lane == 63) ws[wv] = inc;
    __syncthreads();
    int wbase = 0;
    for (int k = 0; k < wv; ++k) wbase += ws[k];
    if (t < NBUCK) {
      int excl = wbase + inc - v;
      lscan[t] = excl;
      lpos[t] = excl;
      rsv[t] = (v > 0) ? atomicAdd(&bucket_cnt[t], v) : 0;
    }
  }
  __syncthreads();
  for (int j = t; j < cnt; j += 256) {
    int s = srcA[e0 + j], d = dstA[e0 + j];
    int p = atomicAdd(&lpos[d >> BUCKET_BITS], 1);
    ent[p] = make_int2(s, d);
  }
  __syncthreads();
  for (int j = t; j < cnt; j += 256) {
    int2 E = ent[j];
    int b = E.y >> BUCKET_BITS;
    int pos = rsv[b] + (j - lscan[b]);
    if (pos < BUCK_CAP)
      binned[b * BUCK_CAP + pos] = (E.x << BUCKET_BITS) | (E.y & (BUCKET_NODES - 1));
  }
}

// per-bucket degrees + padded bucket totals
__global__ __launch_bounds__(512) void k_deg(const int* __restrict__ binned,
                                             const int* __restrict__ bucket_cnt,
                                             int* __restrict__ degg, int* __restrict__ pad_cnt) {
  __shared__ int deg[BUCKET_NODES];
  __shared__ int ws[8];
  int b = blockIdx.x, t = threadIdx.x;
  int cnt = min(bucket_cnt[b], BUCK_CAP);
  deg[t] = 0;
  __syncthreads();
  for (int j = t; j < cnt; j += 512) atomicAdd(&deg[binned[b * BUCK_CAP + j] & (BUCKET_NODES - 1)], 1);
  __syncthreads();
  int n0 = b * BUCKET_NODES;
  int nn = min(BUCKET_NODES, N_NODES - n0);
  int d = (t < nn) ? deg[t] : 0;
  if (t < nn) degg[n0 + t] = d;
  int dp = (d + 7) & ~7;
  int lane = t & 63, wv = t >> 6;
  for (int q = 1; q < 64; q <<= 1) dp += __shfl_xor(dp, q);
  if (lane == 0) ws[wv] = dp;
  __syncthreads();
  if (t == 0) {
    int tot = 0;
    for (int k = 0; k < 8; ++k) tot += ws[k];
    pad_cnt[b] = tot;
  }
}

__global__ __launch_bounds__(256) void k_bucket_scan(const int* __restrict__ pad_cnt,
                                                     int* __restrict__ bucket_base,
                                                     int* __restrict__ off_last) {
  __shared__ int ws[4];
  int t = threadIdx.x;
  int lane = t & 63, wv = t >> 6;
  int v = (t < NBUCK) ? pad_cnt[t] : 0;
  int inc = v;
  for (int d = 1; d < 64; d <<= 1) { int x = __shfl_up(inc, d); if (lane >= d) inc += x; }
  if (lane == 63) ws[wv] = inc;
  __syncthreads();
  int wbase = 0;
  for (int k = 0; k < wv; ++k) wbase += ws[k];
  if (t < NBUCK) bucket_base[t] = wbase + inc - v;
  if (t == NBUCK - 1) *off_last = wbase + inc;
}

// per-bucket padded CSR fill
__global__ __launch_bounds__(512) void k_csr(const int* __restrict__ binned,
                                             const int* __restrict__ bucket_cnt,
                                             const int* __restrict__ bucket_base,
                                             const int* __restrict__ degg,
                                             int* __restrict__ off, int* __restrict__ srcs) {
  __shared__ int sAb[BUCKET_NODES];
  __shared__ int sBb[BUCKET_NODES];
  __shared__ int pos[BUCKET_NODES];
  __shared__ int dreal[BUCKET_NODES];
  __shared__ int epk[BUCK_CAP];
  int b = blockIdx.x;
  int t = threadIdx.x;
  int cnt = min(bucket_cnt[b], BUCK_CAP);
  int gbase = bucket_base[b];
  int n0 = b * BUCKET_NODES;
  int nn = min(BUCKET_NODES, N_NODES - n0);
  int d = (t < nn) ? degg[n0 + t] : 0;
  dreal[t] = d;
  int dp = (d + 7) & ~7;
  int* sA = sAb; int* sB = sBb;
  sA[t] = dp;
  __syncthreads();
  for (int q = 1; q < 512; q <<= 1) {
    int x = sA[t];
    if (t >= q) x += sA[t - q];
    sB[t] = x;
    __syncthreads();
    int* tp = sA; sA = sB; sB = tp;
  }
  int ex = sA[t] - dp;   // exclusive padded scan
  pos[t] = ex;
  if (t < nn) off[n0 + t] = gbase + ex;
  __syncthreads();
  for (int j = t; j < cnt; j += 512) {
    int p = binned[b * BUCK_CAP + j];
    epk[j] = p;
  }
  __syncthreads();
  for (int j = t; j < cnt; j += 512) {
    int p = epk[j];
    int q = atomicAdd(&pos[p & (BUCKET_NODES - 1)], 1);
    srcs[gbase + q] = p >> BUCKET_BITS;
  }
  __syncthreads();
  // fill dummy slots with N_NODES (zero row)
  int start = sA[t] - dp;  // recompute exclusive base
  int fill0 = start + dreal[t];
  int fill1 = start + ((dreal[t] + 7) & ~7);
  for (int q = fill0; q < fill1; ++q) srcs[gbase + q] = N_NODES;
}

// out[n][128](bf16) = A[n][K](bf16, A0|A1 split at k=128, optional relu on A0) @ W[K][128]
__global__ __launch_bounds__(256) void k_gemm(
    const ushort* __restrict__ A0, const ushort* __restrict__ A1,
    const float* __restrict__ W, ushort* __restrict__ out, int n, int K, int relu0)
{
  extern __shared__ char smem[];  // W^T swizzled: (k,c) -> byte c*2K + ((2k)^((c&7)<<4))
  const int KC = K * 128;
  for (int idx = threadIdx.x; idx < KC; idx += 256) {
    int k = idx >> 7, c = idx & 127;
    ushort b = f2b(W[idx]);
    *(ushort*)(smem + c * (K * 2) + ((k * 2) ^ ((c & 7) << 4))) = b;
  }
  __syncthreads();

  int lane = threadIdx.x & 63;
  int wv = threadIdx.x >> 6;
  int rowBase = blockIdx.x * 128 + wv * 32;
  int rl = lane & 15;
  int kh = lane >> 4;
  int r0 = rowBase + rl, r1 = r0 + 16;
  int r0c = min(r0, n - 1), r1c = min(r1, n - 1);

  f32x4 acc[2][8];
#pragma unroll
  for (int i = 0; i < 2; ++i)
#pragma unroll
    for (int j = 0; j < 8; ++j)
      acc[i][j] = (f32x4){0.f, 0.f, 0.f, 0.f};

  int nks = K >> 5;
  for (int ks = 0; ks < nks; ++ks) {
    const ushort* Asrc = (ks < 4) ? A0 : A1;
    int kof = ((ks & 3) << 5) + (kh << 3);
    bf16x8 a0 = *(const bf16x8*)(Asrc + (size_t)r0c * 128 + kof);
    bf16x8 a1 = *(const bf16x8*)(Asrc + (size_t)r1c * 128 + kof);
    if (relu0 && ks < 4) {
#pragma unroll
      for (int q = 0; q < 8; ++q) {
        short v0 = a0[q]; a0[q] = (short)(v0 & ~(v0 >> 15));
        short v1 = a1[q]; a1[q] = (short)(v1 & ~(v1 >> 15));
      }
    }
    int kk = (ks << 5) + (kh << 3);
#pragma unroll
    for (int ct = 0; ct < 8; ++ct) {
      int col = (ct << 4) + rl;
      bf16x8 b = *(const bf16x8*)(smem + col * (K * 2) + ((kk * 2) ^ ((col & 7) << 4)));
      acc[0][ct] = __builtin_amdgcn_mfma_f32_16x16x32_bf16(a0, b, acc[0][ct], 0, 0, 0);
      acc[1][ct] = __builtin_amdgcn_mfma_f32_16x16x32_bf16(a1, b, acc[1][ct], 0, 0, 0);
    }
  }
#pragma unroll
  for (int ri = 0; ri < 2; ++ri)
#pragma unroll
    for (int ct = 0; ct < 8; ++ct) {
      int col = (ct << 4) + rl;
#pragma unroll
      for (int j = 0; j < 4; ++j) {
        int row = rowBase + ri * 16 + kh * 4 + j;
        if (row < n) out[(size_t)row * 128 + col] = f2b(acc[ri][ct][j]);
      }
    }
}

// segment sum, padded CSR: 1 wave/node, 2 cols/lane; two-phase unroll-16
__global__ __launch_bounds__(256) void k_aggr(
    const ushort* __restrict__ hlin, const int* __restrict__ off, const int* __restrict__ srcs,
    const float* __restrict__ bias, ushort* __restrict__ hbf, float* __restrict__ outf,
    int n, int first, int last)
{
  int node = blockIdx.x * 4 + (threadIdx.x >> 6);
  if (node >= n) return;
  int lane = threadIdx.x & 63;
  int s = __builtin_amdgcn_readfirstlane(off[node]);
  int e = __builtin_amdgcn_readfirstlane(off[node + 1]);
  float a0 = 0.f, a1 = 0.f;
  int j = s;
  for (; j + 16 <= e; j += 16) {
    int ix[16];
#pragma unroll
    for (int q = 0; q < 16; ++q) ix[q] = srcs[j + q];
    uint32_t u[16];
#pragma unroll
    for (int q = 0; q < 16; ++q)
      u[q] = *(const uint32_t*)(hlin + (size_t)ix[q] * 128 + lane * 2);
#pragma unroll
    for (int q = 0; q < 16; ++q) {
      a0 += __uint_as_float(u[q] << 16);
      a1 += __uint_as_float(u[q] & 0xFFFF0000u);
    }
  }
  if (j < e) {  // remainder is exactly 8 (degrees padded to x8)
    int ix[8];
#pragma unroll
    for (int q = 0; q < 8; ++q) ix[q] = srcs[j + q];
    uint32_t u[8];
#pragma unroll
    for (int q = 0; q < 8; ++q)
      u[q] = *(const uint32_t*)(hlin + (size_t)ix[q] * 128 + lane * 2);
#pragma unroll
    for (int q = 0; q < 8; ++q) {
      a0 += __uint_as_float(u[q] << 16);
      a1 += __uint_as_float(u[q] & 0xFFFF0000u);
    }
  }
  float2 bv = ((const float2*)bias)[lane];
  size_t idx = (size_t)node * 128 + lane * 2;
  float h0, h1;
  if (first) {
    h0 = a0 + bv.x; h1 = a1 + bv.y;
  } else {
    uint32_t up = *(const uint32_t*)(hbf + idx);
    h0 = __uint_as_float(up << 16) + a0 + bv.x;
    h1 = __uint_as_float(up & 0xFFFF0000u) + a1 + bv.y;
  }
  if (last) {
    if (node < N_ROOTS) *(float2*)(outf + idx) = make_float2(h0, h1);
  } else {
    ushort2 r; r.x = f2b(h0); r.y = f2b(h1);
    *(ushort2*)(hbf + idx) = r;
  }
}

extern "C" void kernel_launch(void* const* d_in, const int* in_sizes, int n_in,
                              void* d_out, int out_size, void* d_ws, size_t ws_size,
                              hipStream_t stream) {
  const float* x = (const float*)d_in[0];
  const int* ei  = (const int*)d_in[1];
  const int* src = ei;
  const int* dst = ei + N_EDGES;
  const float* Wp[4] = {(const float*)d_in[4], (const float*)d_in[6],
                        (const float*)d_in[8], (const float*)d_in[10]};
  const float* bp[4] = {(const float*)d_in[5], (const float*)d_in[7],
                        (const float*)d_in[9], (const float*)d_in[11]};

  char* w = (char*)d_ws;
  auto alloc = [&](size_t bytes) {
    char* p = w;
    w += (bytes + 255) & ~(size_t)255;
    return p;
  };
  ushort* x_bf     = (ushort*)alloc((size_t)N_NODES * 128 * 2);
  ushort* hbf      = (ushort*)alloc((size_t)N_NODES * 128 * 2);
  ushort* hlin     = (ushort*)alloc((size_t)(N_NODES + 8) * 128 * 2);  // +zero row
  int*    off      = (int*)   alloc((size_t)(N_NODES + 1) * 4);
  int*    srcs     = (int*)   alloc((size_t)SRCS_CAP * 4);
  int*    binned   = (int*)   alloc((size_t)NBUCK * BUCK_CAP * 4);
  int*    degg     = (int*)   alloc((size_t)N_NODES * 4);
  int*    bucket_cnt  = (int*)alloc((size_t)NBUCK * 4);
  int*    pad_cnt     = (int*)alloc((size_t)NBUCK * 4);
  int*    bucket_base = (int*)alloc((size_t)(NBUCK + 1) * 4);
  if ((size_t)(w - (char*)d_ws) > ws_size) return;

  hipMemsetAsync(bucket_cnt, 0, (size_t)NBUCK * 4, stream);
  hipMemsetAsync(hlin + (size_t)N_NODES * 128, 0, 256, stream);  // zero row for dummy edges
  k_cvt_bf16<<<2048, 256, 0, stream>>>(x, x_bf, N_NODES * 128 / 4);
  k_bin<<<NB_BIN, 256, 0, stream>>>(src, dst, bucket_cnt, binned);
  k_deg<<<NBUCK, 512, 0, stream>>>(binned, bucket_cnt, degg, pad_cnt);
  k_bucket_scan<<<1, 256, 0, stream>>>(pad_cnt, bucket_base, off + N_NODES);
  k_csr<<<NBUCK, 512, 0, stream>>>(binned, bucket_cnt, bucket_base, degg, off, srcs);

  int gblocks = (N_NODES + 127) / 128;
  int ablocks = (N_NODES + 3) / 4;
  // layer 0
  k_gemm<<<gblocks, 256, 128 * 128 * 2, stream>>>(x_bf, x_bf, Wp[0], hlin, N_NODES, 128, 0);
  k_aggr<<<ablocks, 256, 0, stream>>>(hlin, off, srcs, bp[0], hbf, (float*)d_out, N_NODES, 1, 0);
  // layers 1..3
  for (int l = 1; l < 4; ++l) {
    k_gemm<<<gblocks, 256, 256 * 128 * 2, stream>>>(hbf, x_bf, Wp[l], hlin, N_NODES, 256, 1);
    k_aggr<<<ablocks, 256, 0, stream>>>(hlin, off, srcs, bp[l], hbf, (float*)d_out,
                                        N_NODES, 0, (l == 3) ? 1 : 0);
  }
}